// Round 1
// 211.504 us; speedup vs baseline: 1.0823x; 1.0823x over previous
//
#include <hip/hip_runtime.h>

#define SEQ 2048
#define DHEAD 128
#define BK 32
#define NBH 32

typedef __attribute__((ext_vector_type(8))) short bf16x8;
typedef __attribute__((ext_vector_type(4))) short bf16x4;
typedef __attribute__((ext_vector_type(16))) float f32x16;
typedef __attribute__((ext_vector_type(4))) unsigned int u32x4;

__device__ __forceinline__ unsigned short f2bf(float f) {
    unsigned u = __builtin_bit_cast(unsigned, f);
    u += 0x7fffu + ((u >> 16) & 1u);
    return (unsigned short)(u >> 16);
}

__device__ __forceinline__ void gload16(const unsigned short* g, unsigned short* l) {
    __builtin_amdgcn_global_load_lds((const __attribute__((address_space(1))) void*)g,
                                     (__attribute__((address_space(3))) void*)l, 16, 0, 0);
}

// Fused prepass. Blocks 0..1023: K fp32 [bh*128+d][2048] -> bf16 [bh][l][128],
// 16B-chunk XOR-swizzled per row (phys = logical ^ (l&7)). Blocks 1024..5119:
// V fp32 [bh*128+dv][2048] -> bf16 [bh][kt][dv][32], where within each 32-wide
// kl tile the element order is kl with bits 2<->3 swapped (so the attn PV
// B-frag built directly from the 32x32 S^T accumulator registers matches),
// then 16B-chunk swizzled (phys chunk = logical chunk ^ ((dv>>1)&3)).
__global__ __launch_bounds__(256)
void cvt_kernel(const float* __restrict__ kin, const float* __restrict__ vin,
                unsigned short* __restrict__ kout, unsigned short* __restrict__ vout) {
    const int tid = threadIdx.x;
    if (blockIdx.x < 1024) {
        __shared__ unsigned short tileT[DHEAD][66];   // [d][l]
        const int bh = blockIdx.x & 31;
        const int l0 = (blockIdx.x >> 5) * 64;
        const float* ip = kin + (size_t)bh * DHEAD * SEQ;
        unsigned short* opx = kout + ((size_t)bh * SEQ + l0) * DHEAD;
        const int l4 = (tid & 15) * 4;
        const int dq = tid >> 4;
        for (int pass = 0; pass < 8; ++pass) {
            int d = pass * 16 + dq;
            float4 f = *(const float4*)&ip[(size_t)d * SEQ + l0 + l4];
            unsigned lo = (unsigned)f2bf(f.x) | ((unsigned)f2bf(f.y) << 16);
            unsigned hi = (unsigned)f2bf(f.z) | ((unsigned)f2bf(f.w) << 16);
            *(unsigned*)&tileT[d][l4]     = lo;
            *(unsigned*)&tileT[d][l4 + 2] = hi;
        }
        __syncthreads();
        const int lw = tid >> 2;
        const int cw = tid & 3;
        for (int j = 0; j < 4; ++j) {
            int pc = j * 4 + cw;           // phys chunk
            int lc = pc ^ (lw & 7);        // logical chunk
            unsigned short tmp[8];
            for (int k2 = 0; k2 < 8; ++k2) tmp[k2] = tileT[lc * 8 + k2][lw];
            *(bf16x8*)&opx[(size_t)lw * DHEAD + pc * 8] = *(bf16x8*)tmp;
        }
    } else {
        size_t f = ((size_t)(blockIdx.x - 1024) * 256 + tid) * 8;
        int bh  = (int)(f >> 18);
        int rem = (int)(f & 262143);
        int kt  = rem >> 12;
        int r2  = rem & 4095;
        int dv  = r2 >> 5;
        int e0  = r2 & 31;
        const float* src = vin + ((size_t)bh * DHEAD + dv) * SEQ + kt * BK + e0;
        float4 a = *(const float4*)src;
        float4 b = *(const float4*)(src + 4);
        unsigned short p0[4] = {f2bf(a.x), f2bf(a.y), f2bf(a.z), f2bf(a.w)};
        unsigned short p1[4] = {f2bf(b.x), f2bf(b.y), f2bf(b.z), f2bf(b.w)};
        // kl = 16a + 8b + 4h + t  ->  logical position 16a + 8h + 4b + t
        const int aa = e0 >> 4;
        const int bb = (e0 >> 3) & 1;
        const int w  = (dv >> 1) & 3;
        size_t rowb = ((size_t)bh * (SEQ / BK) + kt) * (DHEAD * BK) + (size_t)dv * BK;
        *(bf16x4*)&vout[rowb + (size_t)(((2 * aa) ^ w) * 8 + 4 * bb)]     = *(bf16x4*)p0;
        *(bf16x4*)&vout[rowb + (size_t)(((2 * aa + 1) ^ w) * 8 + 4 * bb)] = *(bf16x4*)p1;
    }
}

// 32x32x16 swapped-operand attention. Each wave owns 32 queries; QK^T is
// computed as mfma(K,Q) so S^T has ql = lane&31 -> the softmax'd accumulator
// registers, cvt_pk-packed in register order, ARE the PV B-frags (P never
// leaves registers: no pS LDS scratch, no lgkmcnt serialization, no
// cross-lane ops). V's kl ordering in the workspace matches via the
// bit2<->3 permutation applied in cvt_kernel.
__global__ __launch_bounds__(256, 2)
void attn_main(const float* __restrict__ q,
               const unsigned short* __restrict__ kTg,
               const unsigned short* __restrict__ vW,
               const float* __restrict__ gamma,
               float* __restrict__ out) {
    __shared__ __attribute__((aligned(16))) unsigned short kS[2][BK * DHEAD];  // [l][d] swizzled
    __shared__ __attribute__((aligned(16))) unsigned short vS[2][DHEAD * BK];  // [dv][kl-perm] swizzled

    const int tid  = threadIdx.x;
    const int wv   = tid >> 6;
    const int lane = tid & 63;
    const int c5   = lane & 31;
    const int hi   = lane >> 5;

    const int bh  = blockIdx.x & 31;   // same-head blocks stride 32 -> same XCD
    const int qlb = blockIdx.x >> 5;   // 0..15
    const size_t base = (size_t)bh * SEQ * DHEAD;

    const float* qp = q + base;              // fp32 [d][2048]
    const unsigned short* kb = kTg + base;   // [l][128] swizzled
    const unsigned short* vb = vW + base;    // [kt][dv][32] permuted+swizzled
    float* op = out + base;                  // [dv][2048]

    const int ql = qlb * 128 + wv * 32 + c5; // this lane's query column
    const float SCL = 0.08838834764831845f * 1.44269504088896340f; // 1/sqrt(128)*log2e

    // prime tile 0 into buffer 0 (DMA flies while Q frags load below)
    gload16(kb + tid * 8,         &kS[0][tid * 8]);
    gload16(kb + (tid + 256) * 8, &kS[0][(tid + 256) * 8]);
    gload16(vb + tid * 8,         &vS[0][tid * 8]);
    gload16(vb + (tid + 256) * 8, &vS[0][(tid + 256) * 8]);

    // Q B-frags (one-time): B[n=ql][k=hi*8+j], d = s*16 + hi*8 + j
    bf16x8 qf[8];
#pragma unroll
    for (int s = 0; s < 8; ++s) {
        bf16x8 t;
#pragma unroll
        for (int j = 0; j < 8; ++j)
            t[j] = (short)f2bf(qp[(size_t)(s * 16 + hi * 8 + j) * SEQ + ql] * SCL);
        qf[s] = t;
    }

    f32x16 accO[4];
#pragma unroll
    for (int t = 0; t < 4; ++t)
#pragma unroll
        for (int i = 0; i < 16; ++i) accO[t][i] = 0.f;
    float lp = 0.f;

    const int ksw = c5 & 7;
    const int vsw = (c5 >> 1) & 3;

    for (int kt = 0; kt < SEQ / BK; ++kt) {
        const int cur = kt & 1;
        __syncthreads();   // buf[cur] landed (prefetch flew during previous compute)

        if (kt + 1 < SEQ / BK) {   // prefetch next tile into buf[cur^1]
            const unsigned short* kg = kb + (size_t)(kt + 1) * (BK * DHEAD);
            gload16(kg + tid * 8,         &kS[cur ^ 1][tid * 8]);
            gload16(kg + (tid + 256) * 8, &kS[cur ^ 1][(tid + 256) * 8]);
            const unsigned short* vg = vb + (size_t)(kt + 1) * (DHEAD * BK);
            gload16(vg + tid * 8,         &vS[cur ^ 1][tid * 8]);
            gload16(vg + (tid + 256) * 8, &vS[cur ^ 1][(tid + 256) * 8]);
        }

        // K A-frags (row = kl = c5) and V A-frags, hoisted
        bf16x8 kf[8], vf[8];
#pragma unroll
        for (int s = 0; s < 8; ++s)
            kf[s] = *(const bf16x8*)&kS[cur][c5 * DHEAD + (((2 * s + hi) ^ ksw) * 8)];
#pragma unroll
        for (int t = 0; t < 4; ++t)
#pragma unroll
            for (int s2 = 0; s2 < 2; ++s2)
                vf[t * 2 + s2] = *(const bf16x8*)&vS[cur][(32 * t + c5) * BK + (((2 * s2 + hi) ^ vsw) * 8)];

        // S^T[kl][ql] = sum_d K[kl][d] * Q[ql][d]  (scale+log2e folded into Q)
        f32x16 sT;
#pragma unroll
        for (int i = 0; i < 16; ++i) sT[i] = 0.f;
#pragma unroll
        for (int s = 0; s < 8; ++s)
            sT = __builtin_amdgcn_mfma_f32_32x32x16_bf16(kf[s], qf[s], sT, 0, 0, 0);

        // fixed-max softmax fully in-register; pack pairs -> PV B-frags
        unsigned pw[8];
#pragma unroll
        for (int i = 0; i < 8; ++i) {
            float pa = exp2f(sT[2 * i]);
            float pb = exp2f(sT[2 * i + 1]);
            lp += pa + pb;
            unsigned r;
            asm("v_cvt_pk_bf16_f32 %0, %1, %2" : "=v"(r) : "v"(pa), "v"(pb));
            pw[i] = r;
        }
        bf16x8 pf0 = __builtin_bit_cast(bf16x8, (u32x4){pw[0], pw[1], pw[2], pw[3]});
        bf16x8 pf1 = __builtin_bit_cast(bf16x8, (u32x4){pw[4], pw[5], pw[6], pw[7]});

        // O[dv][ql] += V . P^T
#pragma unroll
        for (int t = 0; t < 4; ++t) {
            accO[t] = __builtin_amdgcn_mfma_f32_32x32x16_bf16(vf[t * 2],     pf0, accO[t], 0, 0, 0);
            accO[t] = __builtin_amdgcn_mfma_f32_32x32x16_bf16(vf[t * 2 + 1], pf1, accO[t], 0, 0, 0);
        }
    }

    // epilogue: L[ql] = lp(hi=0) + lp(hi=1); normalize, gamma
    const float L = lp + __shfl_xor(lp, 32);
    const float sc = gamma[0] / L;
#pragma unroll
    for (int t = 0; t < 4; ++t)
#pragma unroll
        for (int r = 0; r < 16; ++r) {
            int dvr = 32 * t + (r & 3) + 8 * (r >> 2) + 4 * hi;
            op[(size_t)dvr * SEQ + ql] = accO[t][r] * sc;
        }
}

extern "C" void kernel_launch(void* const* d_in, const int* in_sizes, int n_in,
                              void* d_out, int out_size, void* d_ws, size_t ws_size,
                              hipStream_t stream) {
    (void)in_sizes; (void)n_in; (void)out_size; (void)ws_size;
    const float* q = (const float*)d_in[0];
    const float* k = (const float*)d_in[1];
    const float* v = (const float*)d_in[2];
    const float* g = (const float*)d_in[3];
    float* out = (float*)d_out;

    // ws: kT bf16 (16 MB) | vTiled bf16 (16 MB)
    const size_t PER_T = (size_t)NBH * SEQ * DHEAD;
    unsigned short* kws = (unsigned short*)d_ws;
    unsigned short* vws = kws + PER_T;

    cvt_kernel<<<dim3(1024 + 4096), dim3(256), 0, stream>>>(k, v, kws, vws);
    attn_main<<<dim3(512), dim3(256), 0, stream>>>(q, kws, vws, g, out);
}